// Round 1
// baseline (733.042 us; speedup 1.0000x reference)
//
#include <hip/hip_runtime.h>
#include <stdint.h>

#define T_TOK 4096
#define D_DIM 1024
#define F_DIM 4096
#define NEXP 8
#define BM 128
#define BN 128
#define BK 32
#define CAP 9216      // 8192 pairs + 8*128 padding
#define MT_MAX (CAP / BM)

typedef __attribute__((ext_vector_type(8))) short short8;
typedef __attribute__((ext_vector_type(4))) float f4;
typedef __attribute__((ext_vector_type(4))) unsigned short us4;

// ---- ws layout (bytes) ----
#define WS_CNT     0                         // int[8]
#define WS_CUR     32                        // int[8]
#define WS_SBASE   64                        // int[8]
#define WS_TBASE   96                        // int[9]
#define WS_TOPI    256                       // int[T*2]
#define WS_TOPP    (WS_TOPI + T_TOK*2*4)     // float[T*2]
#define WS_PSLOT   (WS_TOPP + T_TOK*2*4)     // int[T*2]
#define WS_XG      102400                    // bf16 [CAP][D]
#define WS_H       (WS_XG + CAP*D_DIM*2)     // bf16 [CAP][F]
#define WS_Y       (WS_H + CAP*F_DIM*2)      // bf16 [CAP][D]

__device__ __forceinline__ unsigned short f2bf(float f) {
    union { float f; uint32_t u; } c; c.f = f;
    uint32_t r = c.u + 0x7FFFu + ((c.u >> 16) & 1u);
    return (unsigned short)(r >> 16);
}
__device__ __forceinline__ float bf2f(unsigned short h) {
    union { uint32_t u; float f; } c; c.u = ((uint32_t)h) << 16;
    return c.f;
}

// ---------------- gate: fp32 logits, top-2, softmax ----------------
__global__ __launch_bounds__(256) void gate_kernel(
    const float* __restrict__ x, const float* __restrict__ gw,
    const float* __restrict__ gb,
    int* __restrict__ top_idx, float* __restrict__ top_p, int* __restrict__ cnt)
{
    int lane = threadIdx.x & 63;
    int t = blockIdx.x * 4 + (threadIdx.x >> 6);
    const float* xr = x + (size_t)t * D_DIM;
    float acc[8] = {0.f,0.f,0.f,0.f,0.f,0.f,0.f,0.f};
    for (int i = 0; i < 16; ++i) {
        int d = lane + i * 64;
        float xv = xr[d];
        const float* g = gw + d * 8;
        #pragma unroll
        for (int e = 0; e < 8; ++e) acc[e] += xv * g[e];
    }
    #pragma unroll
    for (int e = 0; e < 8; ++e) {
        #pragma unroll
        for (int off = 32; off > 0; off >>= 1)
            acc[e] += __shfl_xor(acc[e], off, 64);
    }
    if (lane == 0) {
        float l[8];
        #pragma unroll
        for (int e = 0; e < 8; ++e) l[e] = acc[e] + gb[e];
        int i0 = 0; float m0 = l[0];
        #pragma unroll
        for (int e = 1; e < 8; ++e) if (l[e] > m0) { m0 = l[e]; i0 = e; }
        int i1 = -1; float m1 = -3.4e38f;
        #pragma unroll
        for (int e = 0; e < 8; ++e) if (e != i0 && l[e] > m1) { m1 = l[e]; i1 = e; }
        float p0 = 1.f / (1.f + expf(m1 - m0));   // = e^m0/(e^m0+e^m1)
        top_idx[t*2]   = i0; top_idx[t*2+1] = i1;
        top_p[t*2]     = p0; top_p[t*2+1]   = 1.f - p0;
        atomicAdd(&cnt[i0], 1);
        atomicAdd(&cnt[i1], 1);
    }
}

// ---------------- bases: pad counts to BM, prefix sums ----------------
__global__ void bases_kernel(const int* __restrict__ cnt,
                             int* __restrict__ sbase, int* __restrict__ tbase)
{
    if (threadIdx.x == 0) {
        int b = 0, tb = 0;
        tbase[0] = 0;
        for (int e = 0; e < 8; ++e) {
            sbase[e] = b;
            int mt = (cnt[e] + BM - 1) / BM;
            b  += mt * BM;
            tb += mt;
            tbase[e + 1] = tb;
        }
    }
}

// ---------------- gather: slot assign + x row -> bf16 ----------------
__global__ __launch_bounds__(256) void gather_kernel(
    const float* __restrict__ x, const int* __restrict__ top_idx,
    int* __restrict__ cursor, const int* __restrict__ sbase,
    int* __restrict__ pair_slot, uint16_t* __restrict__ xg)
{
    __shared__ int s_slot;
    int p = blockIdx.x;
    int t = p >> 1;
    if (threadIdx.x == 0) {
        int e = top_idx[p];
        int slot = sbase[e] + atomicAdd(&cursor[e], 1);
        pair_slot[p] = slot;
        s_slot = slot;
    }
    __syncthreads();
    int slot = s_slot;
    const f4* src = (const f4*)(x + (size_t)t * D_DIM);
    uint16_t* dst = xg + (size_t)slot * D_DIM;
    int i = threadIdx.x;  // 256 threads x 4 elems = 1024
    f4 v = src[i];
    us4 o;
    o.x = f2bf(v[0]); o.y = f2bf(v[1]); o.z = f2bf(v[2]); o.w = f2bf(v[3]);
    *(us4*)(dst + i * 4) = o;
}

// ---------------- grouped GEMM: C[M,N] = A[M,K](bf16) * B[K,N](fp32->bf16) ----------------
// 128x128 tile, BK=32, 4 waves (each 64x64 = 4x4 frags of 16x16x32 MFMA).
// A: global_load_lds 16B, LDS [128][32] with k-block XOR swizzle ((r>>1)&3)
//    applied by pre-swizzling the GLOBAL source (linear LDS dest).
// B: reg-staged fp32->bf16 TRANSPOSED into LDS [n][k], row stride 80B
//    (conflict-free b128 reads; ~4-way on writes).
template<bool RELU>
__global__ __launch_bounds__(256, 2) void moe_gemm(
    const uint16_t* __restrict__ A,   // [CAP][K] bf16
    const float*    __restrict__ Bw,  // [NEXP][K][N] fp32
    const float*    __restrict__ bias,// [NEXP][N]
    uint16_t*       __restrict__ Cc,  // [CAP][N] bf16
    const int* __restrict__ tbase, const int* __restrict__ sbase,
    int K, int N)
{
    __shared__ uint16_t As[BM][BK];   // 8 KB
    __shared__ uint16_t Bs[BN][40];   // 10 KB, [n][k] stride 80B

    int mt = blockIdx.x;
    if (mt >= tbase[8]) return;
    int e = 0;
    while (mt >= tbase[e + 1]) ++e;
    int row0 = sbase[e] + (mt - tbase[e]) * BM;
    int n0 = blockIdx.y * BN;
    const float* Be = Bw + (size_t)e * K * N;

    int tid = threadIdx.x;
    int wid = tid >> 6, lane = tid & 63;
    int wrow = (wid >> 1) * 64, wcol = (wid & 1) * 64;

    f4 acc[4][4] = {};

    // B staging map: kp=k-pair (k=kp*2,kp*2+1), ng*8+i = n
    int kp = tid & 15;
    int ng = tid >> 4;
    const float* bptr = Be + (size_t)(kp * 2) * N + n0 + ng * 8;

    int ov0 = wid * 2048 + lane * 16;  // linear LDS byte for A staging

    // fragment read byte offsets (fixed per thread)
    int abyte[4], bbyte[4];
    #pragma unroll
    for (int m = 0; m < 4; ++m) {
        int r = wrow + m * 16 + (lane & 15);
        abyte[m] = r * 64 + (((lane >> 4) * 16) ^ (((r >> 1) & 3) << 4));
    }
    #pragma unroll
    for (int n = 0; n < 4; ++n) {
        int c = wcol + n * 16 + (lane & 15);
        bbyte[n] = c * 80 + (lane >> 4) * 16;
    }
    const char* As0 = (const char*)&As[0][0];
    const char* Bs0 = (const char*)&Bs[0][0];

    for (int kt = 0; kt < K; kt += BK) {
        // ---- stage A (2 x 16B global_load_lds, pre-swizzled source) ----
        #pragma unroll
        for (int j = 0; j < 2; ++j) {
            int ov  = ov0 + j * 1024;
            int row = ov >> 6;
            int kb  = (ov & 63) ^ (((row >> 1) & 3) << 4);
            const uint16_t* gp = A + (size_t)(row0 + row) * K + kt + (kb >> 1);
            __builtin_amdgcn_global_load_lds(
                (const __attribute__((address_space(1))) void*)gp,
                (__attribute__((address_space(3))) void*)((char*)&As[0][0] + ov),
                16, 0, 0);
        }
        // ---- stage B: 4x dwordx4 fp32 -> bf16 pairs -> transposed LDS ----
        {
            const float* bp = bptr + (size_t)kt * N;
            f4 v0 = *(const f4*)bp;
            f4 v1 = *(const f4*)(bp + 4);
            f4 w0 = *(const f4*)(bp + N);
            f4 w1 = *(const f4*)(bp + N + 4);
            float va[8], wa[8];
            *(f4*)&va[0] = v0; *(f4*)&va[4] = v1;
            *(f4*)&wa[0] = w0; *(f4*)&wa[4] = w1;
            #pragma unroll
            for (int i = 0; i < 8; ++i) {
                int n = ng * 8 + i;
                uint32_t pk = ((uint32_t)f2bf(wa[i]) << 16) | (uint32_t)f2bf(va[i]);
                *(uint32_t*)((char*)&Bs[0][0] + n * 80 + kp * 4) = pk;
            }
        }
        __syncthreads();
        // ---- compute ----
        short8 af[4], bfr[4];
        #pragma unroll
        for (int m = 0; m < 4; ++m) af[m] = *(const short8*)(As0 + abyte[m]);
        #pragma unroll
        for (int n = 0; n < 4; ++n) bfr[n] = *(const short8*)(Bs0 + bbyte[n]);
        #pragma unroll
        for (int m = 0; m < 4; ++m)
            #pragma unroll
            for (int n = 0; n < 4; ++n)
                acc[m][n] = __builtin_amdgcn_mfma_f32_16x16x32_bf16(
                    af[m], bfr[n], acc[m][n], 0, 0, 0);
        __syncthreads();
    }

    // ---- epilogue: +bias (opt ReLU) -> bf16 ----
    #pragma unroll
    for (int n = 0; n < 4; ++n) {
        int c = wcol + n * 16 + (lane & 15);
        float bv = bias[(size_t)e * N + n0 + c];
        #pragma unroll
        for (int m = 0; m < 4; ++m) {
            int rb = wrow + m * 16 + (lane >> 4) * 4;
            #pragma unroll
            for (int r = 0; r < 4; ++r) {
                float v = acc[m][n][r] + bv;
                if (RELU) v = fmaxf(v, 0.f);
                Cc[(size_t)(row0 + rb + r) * N + n0 + c] = f2bf(v);
            }
        }
    }
}

// ---------------- combine: out[t] = p0*Y[s0] + p1*Y[s1] ----------------
__global__ __launch_bounds__(256) void combine_kernel(
    const uint16_t* __restrict__ Y, const int* __restrict__ pair_slot,
    const float* __restrict__ top_p, float* __restrict__ out)
{
    int t = blockIdx.x;
    int s0 = pair_slot[t*2], s1 = pair_slot[t*2+1];
    float p0 = top_p[t*2],  p1 = top_p[t*2+1];
    int i = threadIdx.x * 4;
    us4 a = *(const us4*)(Y + (size_t)s0 * D_DIM + i);
    us4 b = *(const us4*)(Y + (size_t)s1 * D_DIM + i);
    f4 o;
    o[0] = p0 * bf2f(a.x) + p1 * bf2f(b.x);
    o[1] = p0 * bf2f(a.y) + p1 * bf2f(b.y);
    o[2] = p0 * bf2f(a.z) + p1 * bf2f(b.z);
    o[3] = p0 * bf2f(a.w) + p1 * bf2f(b.w);
    *(f4*)(out + (size_t)t * D_DIM + i) = o;
}

extern "C" void kernel_launch(void* const* d_in, const int* in_sizes, int n_in,
                              void* d_out, int out_size, void* d_ws, size_t ws_size,
                              hipStream_t stream)
{
    const float* x  = (const float*)d_in[0];
    const float* gw = (const float*)d_in[1];
    const float* gb = (const float*)d_in[2];
    const float* w1 = (const float*)d_in[3];
    const float* b1 = (const float*)d_in[4];
    const float* w2 = (const float*)d_in[5];
    const float* b2 = (const float*)d_in[6];
    float* out = (float*)d_out;

    char* ws = (char*)d_ws;
    int*   cnt   = (int*)(ws + WS_CNT);
    int*   cur   = (int*)(ws + WS_CUR);
    int*   sbase = (int*)(ws + WS_SBASE);
    int*   tbase = (int*)(ws + WS_TBASE);
    int*   topi  = (int*)(ws + WS_TOPI);
    float* topp  = (float*)(ws + WS_TOPP);
    int*   pslot = (int*)(ws + WS_PSLOT);
    uint16_t* xg = (uint16_t*)(ws + WS_XG);
    uint16_t* H  = (uint16_t*)(ws + WS_H);
    uint16_t* Y  = (uint16_t*)(ws + WS_Y);

    hipMemsetAsync(ws, 0, 64, stream);  // cnt + cursor
    gate_kernel<<<T_TOK / 4, 256, 0, stream>>>(x, gw, gb, topi, topp, cnt);
    bases_kernel<<<1, 64, 0, stream>>>(cnt, sbase, tbase);
    gather_kernel<<<T_TOK * 2, 256, 0, stream>>>(x, topi, cur, sbase, pslot, xg);
    moe_gemm<true ><<<dim3(MT_MAX, F_DIM / BN), 256, 0, stream>>>(
        xg, w1, b1, H, tbase, sbase, D_DIM, F_DIM);
    moe_gemm<false><<<dim3(MT_MAX, D_DIM / BN), 256, 0, stream>>>(
        H, w2, b2, Y, tbase, sbase, F_DIM, D_DIM);
    combine_kernel<<<T_TOK, 256, 0, stream>>>(Y, pslot, topp, out);
}

// Round 2
// 562.340 us; speedup vs baseline: 1.3036x; 1.3036x over previous
//
#include <hip/hip_runtime.h>
#include <stdint.h>

#define T_TOK 4096
#define D_DIM 1024
#define F_DIM 4096
#define NEXP 8
#define BM 128
#define BN 128
#define BK 32
#define CAP 9216      // 8192 pairs + 8*128 padding
#define MT_MAX (CAP / BM)

typedef __attribute__((ext_vector_type(8))) short short8;
typedef __attribute__((ext_vector_type(4))) float f4;
typedef __attribute__((ext_vector_type(4))) unsigned short us4;

// ---- ws layout (bytes) ----
#define WS_CNT     0                         // int[8]
#define WS_CUR     32                        // int[8]
#define WS_SBASE   64                        // int[8]
#define WS_TBASE   96                        // int[9]
#define WS_TOPI    256                       // int[T*2]
#define WS_TOPP    (WS_TOPI + T_TOK*2*4)     // float[T*2]
#define WS_PSLOT   (WS_TOPP + T_TOK*2*4)     // int[T*2]
#define WS_XG      102400                    // bf16 [CAP][D]
#define WS_H       (WS_XG + (size_t)CAP*D_DIM*2)     // bf16 [CAP][F]
#define WS_Y       (WS_H + (size_t)CAP*F_DIM*2)      // bf16 [CAP][D]
#define WS_WT      (WS_Y + (size_t)CAP*D_DIM*2)      // bf16 [E][N][K] (67 MB, reused)
#define WT_BYTES   ((size_t)NEXP*D_DIM*F_DIM*2)

__device__ __forceinline__ unsigned short f2bf(float f) {
    union { float f; uint32_t u; } c; c.f = f;
    uint32_t r = c.u + 0x7FFFu + ((c.u >> 16) & 1u);
    return (unsigned short)(r >> 16);
}
__device__ __forceinline__ float bf2f(unsigned short h) {
    union { uint32_t u; float f; } c; c.u = ((uint32_t)h) << 16;
    return c.f;
}

// ---------------- gate: fp32 logits, top-2, softmax ----------------
__global__ __launch_bounds__(256) void gate_kernel(
    const float* __restrict__ x, const float* __restrict__ gw,
    const float* __restrict__ gb,
    int* __restrict__ top_idx, float* __restrict__ top_p, int* __restrict__ cnt)
{
    int lane = threadIdx.x & 63;
    int t = blockIdx.x * 4 + (threadIdx.x >> 6);
    const float* xr = x + (size_t)t * D_DIM;
    float acc[8] = {0.f,0.f,0.f,0.f,0.f,0.f,0.f,0.f};
    for (int i = 0; i < 16; ++i) {
        int d = lane + i * 64;
        float xv = xr[d];
        const float* g = gw + d * 8;
        #pragma unroll
        for (int e = 0; e < 8; ++e) acc[e] += xv * g[e];
    }
    #pragma unroll
    for (int e = 0; e < 8; ++e) {
        #pragma unroll
        for (int off = 32; off > 0; off >>= 1)
            acc[e] += __shfl_xor(acc[e], off, 64);
    }
    if (lane == 0) {
        float l[8];
        #pragma unroll
        for (int e = 0; e < 8; ++e) l[e] = acc[e] + gb[e];
        int i0 = 0; float m0 = l[0];
        #pragma unroll
        for (int e = 1; e < 8; ++e) if (l[e] > m0) { m0 = l[e]; i0 = e; }
        int i1 = -1; float m1 = -3.4e38f;
        #pragma unroll
        for (int e = 0; e < 8; ++e) if (e != i0 && l[e] > m1) { m1 = l[e]; i1 = e; }
        float p0 = 1.f / (1.f + expf(m1 - m0));
        top_idx[t*2]   = i0; top_idx[t*2+1] = i1;
        top_p[t*2]     = p0; top_p[t*2+1]   = 1.f - p0;
        atomicAdd(&cnt[i0], 1);
        atomicAdd(&cnt[i1], 1);
    }
}

// ---------------- bases ----------------
__global__ void bases_kernel(const int* __restrict__ cnt,
                             int* __restrict__ sbase, int* __restrict__ tbase)
{
    if (threadIdx.x == 0) {
        int b = 0, tb = 0;
        tbase[0] = 0;
        for (int e = 0; e < 8; ++e) {
            sbase[e] = b;
            int mt = (cnt[e] + BM - 1) / BM;
            b  += mt * BM;
            tb += mt;
            tbase[e + 1] = tb;
        }
    }
}

// ---------------- gather ----------------
__global__ __launch_bounds__(256) void gather_kernel(
    const float* __restrict__ x, const int* __restrict__ top_idx,
    int* __restrict__ cursor, const int* __restrict__ sbase,
    int* __restrict__ pair_slot, uint16_t* __restrict__ xg)
{
    __shared__ int s_slot;
    int p = blockIdx.x;
    int t = p >> 1;
    if (threadIdx.x == 0) {
        int e = top_idx[p];
        int slot = sbase[e] + atomicAdd(&cursor[e], 1);
        pair_slot[p] = slot;
        s_slot = slot;
    }
    __syncthreads();
    int slot = s_slot;
    const f4* src = (const f4*)(x + (size_t)t * D_DIM);
    uint16_t* dst = xg + (size_t)slot * D_DIM;
    int i = threadIdx.x;
    f4 v = src[i];
    us4 o;
    o.x = f2bf(v[0]); o.y = f2bf(v[1]); o.z = f2bf(v[2]); o.w = f2bf(v[3]);
    *(us4*)(dst + i * 4) = o;
}

// ---------------- weight convert+transpose: fp32 [E][K][N] -> bf16 [E][N][K] ----------------
__global__ __launch_bounds__(256) void convT_kernel(
    const float* __restrict__ W, uint16_t* __restrict__ WT, int K, int N)
{
    __shared__ float t[32][33];
    int e = blockIdx.z;
    int n0 = blockIdx.x * 32, k0 = blockIdx.y * 32;
    const float* src = W + (size_t)e * K * N + (size_t)k0 * N + n0;
    int r = threadIdx.x >> 3, cq = threadIdx.x & 7;
    f4 v = *(const f4*)(src + (size_t)r * N + cq * 4);
    t[r][cq*4+0] = v[0]; t[r][cq*4+1] = v[1];
    t[r][cq*4+2] = v[2]; t[r][cq*4+3] = v[3];
    __syncthreads();
    us4 o;
    o.x = f2bf(t[cq*4+0][r]); o.y = f2bf(t[cq*4+1][r]);
    o.z = f2bf(t[cq*4+2][r]); o.w = f2bf(t[cq*4+3][r]);
    *(us4*)(WT + (size_t)e * N * K + (size_t)(n0 + r) * K + k0 + cq * 4) = o;
}

// ---------------- grouped GEMM v2: A[M,K] bf16 x WT[N,K] bf16 -> C[M,N] bf16 ----------------
// m97 structure: 128x128 tile, BK=32, 4 waves of 4x4 16x16x32 frags.
// Both operands staged with global_load_lds(16B), linear LDS dest +
// XOR-pre-swizzled global source; reads apply the same swizzle (2-way = free).
template<bool RELU>
__global__ __launch_bounds__(256, 2) void moe_gemm(
    const uint16_t* __restrict__ A,   // [CAP][K] bf16
    const uint16_t* __restrict__ Bt,  // [NEXP][N][K] bf16
    const float*    __restrict__ bias,// [NEXP][N]
    uint16_t*       __restrict__ Cc,  // [CAP][N] bf16
    const int* __restrict__ tbase, const int* __restrict__ sbase,
    int K, int N)
{
    __shared__ uint16_t As[BM][BK];   // 8 KB
    __shared__ uint16_t Bs[BN][BK];   // 8 KB

    int mt = blockIdx.x;
    if (mt >= tbase[8]) return;
    int e = 0;
    while (mt >= tbase[e + 1]) ++e;
    int row0 = sbase[e] + (mt - tbase[e]) * BM;
    int n0 = blockIdx.y * BN;
    const uint16_t* Be = Bt + (size_t)e * N * K + (size_t)n0 * K;

    int tid = threadIdx.x;
    int wid = tid >> 6, lane = tid & 63;
    int wrow = (wid >> 1) * 64, wcol = (wid & 1) * 64;

    f4 acc[4][4] = {};

    // staging geometry: shot j covers LDS bytes [j*4096, j*4096+4096)
    int ovb = tid * 16;
    int rowA[2], koffA[2];
    #pragma unroll
    for (int j = 0; j < 2; ++j) {
        int ov = ovb + j * 4096;
        int row = ov >> 6;
        int cb  = (ov >> 4) & 3;
        rowA[j]  = row;
        koffA[j] = (cb ^ ((row >> 1) & 3)) << 3;   // bf16 elements
    }

    // fragment read byte offsets
    int abyte[4], bbyte[4];
    #pragma unroll
    for (int m = 0; m < 4; ++m) {
        int r = wrow + m * 16 + (lane & 15);
        abyte[m] = r * 64 + ((((lane >> 4) ^ ((r >> 1) & 3))) << 4);
    }
    #pragma unroll
    for (int n = 0; n < 4; ++n) {
        int c = wcol + n * 16 + (lane & 15);
        bbyte[n] = c * 64 + ((((lane >> 4) ^ ((c >> 1) & 3))) << 4);
    }
    const char* As0 = (const char*)&As[0][0];
    const char* Bs0 = (const char*)&Bs[0][0];

    for (int kt = 0; kt < K; kt += BK) {
        #pragma unroll
        for (int j = 0; j < 2; ++j) {
            const uint16_t* gpA = A + (size_t)(row0 + rowA[j]) * K + kt + koffA[j];
            __builtin_amdgcn_global_load_lds(
                (const __attribute__((address_space(1))) void*)gpA,
                (__attribute__((address_space(3))) void*)((char*)&As[0][0] + ovb + j * 4096),
                16, 0, 0);
            const uint16_t* gpB = Be + (size_t)rowA[j] * K + kt + koffA[j];
            __builtin_amdgcn_global_load_lds(
                (const __attribute__((address_space(1))) void*)gpB,
                (__attribute__((address_space(3))) void*)((char*)&Bs[0][0] + ovb + j * 4096),
                16, 0, 0);
        }
        __syncthreads();
        short8 af[4], bfr[4];
        #pragma unroll
        for (int m = 0; m < 4; ++m) af[m] = *(const short8*)(As0 + abyte[m]);
        #pragma unroll
        for (int n = 0; n < 4; ++n) bfr[n] = *(const short8*)(Bs0 + bbyte[n]);
        #pragma unroll
        for (int m = 0; m < 4; ++m)
            #pragma unroll
            for (int n = 0; n < 4; ++n)
                acc[m][n] = __builtin_amdgcn_mfma_f32_16x16x32_bf16(
                    af[m], bfr[n], acc[m][n], 0, 0, 0);
        __syncthreads();
    }

    #pragma unroll
    for (int n = 0; n < 4; ++n) {
        int c = wcol + n * 16 + (lane & 15);
        float bv = bias[(size_t)e * N + n0 + c];
        #pragma unroll
        for (int m = 0; m < 4; ++m) {
            int rb = wrow + m * 16 + (lane >> 4) * 4;
            #pragma unroll
            for (int r = 0; r < 4; ++r) {
                float v = acc[m][n][r] + bv;
                if (RELU) v = fmaxf(v, 0.f);
                Cc[(size_t)(row0 + rb + r) * N + n0 + c] = f2bf(v);
            }
        }
    }
}

// ---------------- legacy GEMM (fp32 B staging) — ws fallback ----------------
template<bool RELU>
__global__ __launch_bounds__(256, 2) void moe_gemm_legacy(
    const uint16_t* __restrict__ A, const float* __restrict__ Bw,
    const float* __restrict__ bias, uint16_t* __restrict__ Cc,
    const int* __restrict__ tbase, const int* __restrict__ sbase,
    int K, int N)
{
    __shared__ uint16_t As[BM][BK];
    __shared__ uint16_t Bs[BN][40];

    int mt = blockIdx.x;
    if (mt >= tbase[8]) return;
    int e = 0;
    while (mt >= tbase[e + 1]) ++e;
    int row0 = sbase[e] + (mt - tbase[e]) * BM;
    int n0 = blockIdx.y * BN;
    const float* Be = Bw + (size_t)e * K * N;

    int tid = threadIdx.x;
    int wid = tid >> 6, lane = tid & 63;
    int wrow = (wid >> 1) * 64, wcol = (wid & 1) * 64;

    f4 acc[4][4] = {};
    int kp = tid & 15;
    int ng = tid >> 4;
    const float* bptr = Be + (size_t)(kp * 2) * N + n0 + ng * 8;
    int ov0 = wid * 2048 + lane * 16;

    int abyte[4], bbyte[4];
    #pragma unroll
    for (int m = 0; m < 4; ++m) {
        int r = wrow + m * 16 + (lane & 15);
        abyte[m] = r * 64 + (((lane >> 4) * 16) ^ (((r >> 1) & 3) << 4));
    }
    #pragma unroll
    for (int n = 0; n < 4; ++n) {
        int c = wcol + n * 16 + (lane & 15);
        bbyte[n] = c * 80 + (lane >> 4) * 16;
    }
    const char* As0 = (const char*)&As[0][0];
    const char* Bs0 = (const char*)&Bs[0][0];

    for (int kt = 0; kt < K; kt += BK) {
        #pragma unroll
        for (int j = 0; j < 2; ++j) {
            int ov  = ov0 + j * 1024;
            int row = ov >> 6;
            int kb  = (ov & 63) ^ (((row >> 1) & 3) << 4);
            const uint16_t* gp = A + (size_t)(row0 + row) * K + kt + (kb >> 1);
            __builtin_amdgcn_global_load_lds(
                (const __attribute__((address_space(1))) void*)gp,
                (__attribute__((address_space(3))) void*)((char*)&As[0][0] + ov),
                16, 0, 0);
        }
        {
            const float* bp = bptr + (size_t)kt * N;
            f4 v0 = *(const f4*)bp;
            f4 v1 = *(const f4*)(bp + 4);
            f4 w0 = *(const f4*)(bp + N);
            f4 w1 = *(const f4*)(bp + N + 4);
            float va[8], wa[8];
            *(f4*)&va[0] = v0; *(f4*)&va[4] = v1;
            *(f4*)&wa[0] = w0; *(f4*)&wa[4] = w1;
            #pragma unroll
            for (int i = 0; i < 8; ++i) {
                int n = ng * 8 + i;
                uint32_t pk = ((uint32_t)f2bf(wa[i]) << 16) | (uint32_t)f2bf(va[i]);
                *(uint32_t*)((char*)&Bs[0][0] + n * 80 + kp * 4) = pk;
            }
        }
        __syncthreads();
        short8 af[4], bfr[4];
        #pragma unroll
        for (int m = 0; m < 4; ++m) af[m] = *(const short8*)(As0 + abyte[m]);
        #pragma unroll
        for (int n = 0; n < 4; ++n) bfr[n] = *(const short8*)(Bs0 + bbyte[n]);
        #pragma unroll
        for (int m = 0; m < 4; ++m)
            #pragma unroll
            for (int n = 0; n < 4; ++n)
                acc[m][n] = __builtin_amdgcn_mfma_f32_16x16x32_bf16(
                    af[m], bfr[n], acc[m][n], 0, 0, 0);
        __syncthreads();
    }

    #pragma unroll
    for (int n = 0; n < 4; ++n) {
        int c = wcol + n * 16 + (lane & 15);
        float bv = bias[(size_t)e * N + n0 + c];
        #pragma unroll
        for (int m = 0; m < 4; ++m) {
            int rb = wrow + m * 16 + (lane >> 4) * 4;
            #pragma unroll
            for (int r = 0; r < 4; ++r) {
                float v = acc[m][n][r] + bv;
                if (RELU) v = fmaxf(v, 0.f);
                Cc[(size_t)(row0 + rb + r) * N + n0 + c] = f2bf(v);
            }
        }
    }
}

// ---------------- combine ----------------
__global__ __launch_bounds__(256) void combine_kernel(
    const uint16_t* __restrict__ Y, const int* __restrict__ pair_slot,
    const float* __restrict__ top_p, float* __restrict__ out)
{
    int t = blockIdx.x;
    int s0 = pair_slot[t*2], s1 = pair_slot[t*2+1];
    float p0 = top_p[t*2],  p1 = top_p[t*2+1];
    int i = threadIdx.x * 4;
    us4 a = *(const us4*)(Y + (size_t)s0 * D_DIM + i);
    us4 b = *(const us4*)(Y + (size_t)s1 * D_DIM + i);
    f4 o;
    o[0] = p0 * bf2f(a.x) + p1 * bf2f(b.x);
    o[1] = p0 * bf2f(a.y) + p1 * bf2f(b.y);
    o[2] = p0 * bf2f(a.z) + p1 * bf2f(b.z);
    o[3] = p0 * bf2f(a.w) + p1 * bf2f(b.w);
    *(f4*)(out + (size_t)t * D_DIM + i) = o;
}

extern "C" void kernel_launch(void* const* d_in, const int* in_sizes, int n_in,
                              void* d_out, int out_size, void* d_ws, size_t ws_size,
                              hipStream_t stream)
{
    const float* x  = (const float*)d_in[0];
    const float* gw = (const float*)d_in[1];
    const float* gb = (const float*)d_in[2];
    const float* w1 = (const float*)d_in[3];
    const float* b1 = (const float*)d_in[4];
    const float* w2 = (const float*)d_in[5];
    const float* b2 = (const float*)d_in[6];
    float* out = (float*)d_out;

    char* ws = (char*)d_ws;
    int*   cnt   = (int*)(ws + WS_CNT);
    int*   cur   = (int*)(ws + WS_CUR);
    int*   sbase = (int*)(ws + WS_SBASE);
    int*   tbase = (int*)(ws + WS_TBASE);
    int*   topi  = (int*)(ws + WS_TOPI);
    float* topp  = (float*)(ws + WS_TOPP);
    int*   pslot = (int*)(ws + WS_PSLOT);
    uint16_t* xg = (uint16_t*)(ws + WS_XG);
    uint16_t* H  = (uint16_t*)(ws + WS_H);
    uint16_t* Y  = (uint16_t*)(ws + WS_Y);
    uint16_t* WT = (uint16_t*)(ws + WS_WT);

    hipMemsetAsync(ws, 0, 64, stream);
    gate_kernel<<<T_TOK / 4, 256, 0, stream>>>(x, gw, gb, topi, topp, cnt);
    bases_kernel<<<1, 64, 0, stream>>>(cnt, sbase, tbase);
    gather_kernel<<<T_TOK * 2, 256, 0, stream>>>(x, topi, cur, sbase, pslot, xg);

    if (ws_size >= WS_WT + WT_BYTES) {
        // fast path: bf16 transposed weights, both GEMM operands via global_load_lds
        convT_kernel<<<dim3(F_DIM/32, D_DIM/32, NEXP), 256, 0, stream>>>(w1, WT, D_DIM, F_DIM);
        moe_gemm<true ><<<dim3(MT_MAX, F_DIM / BN), 256, 0, stream>>>(
            xg, WT, b1, H, tbase, sbase, D_DIM, F_DIM);
        convT_kernel<<<dim3(D_DIM/32, F_DIM/32, NEXP), 256, 0, stream>>>(w2, WT, F_DIM, D_DIM);
        moe_gemm<false><<<dim3(MT_MAX, D_DIM / BN), 256, 0, stream>>>(
            H, WT, b2, Y, tbase, sbase, F_DIM, D_DIM);
    } else {
        // fallback: round-1 path (ws too small for WT)
        moe_gemm_legacy<true ><<<dim3(MT_MAX, F_DIM / BN), 256, 0, stream>>>(
            xg, w1, b1, H, tbase, sbase, D_DIM, F_DIM);
        moe_gemm_legacy<false><<<dim3(MT_MAX, D_DIM / BN), 256, 0, stream>>>(
            H, w2, b2, Y, tbase, sbase, F_DIM, D_DIM);
    }
    combine_kernel<<<T_TOK, 256, 0, stream>>>(Y, pslot, topp, out);
}